// Round 4
// baseline (58.307 us; speedup 1.0000x reference)
//
#include <hip/hip_runtime.h>
#include <hip/hip_bf16.h>

#define N_EDGES 1600000
#define D_IN    128
#define D_HID   256
#define NB_SCAN 256          // scan blocks (== threads in k_count's list-build)
#define NB_CNT  512          // count blocks
#define MAXG    512          // global match cap
#define PBM_STRIDE 72        // per-scan-block region: count + up to 64 srcs

// ws int layout:
//  [16]            = m (compact match count), written by k_count block 0
//  [512 .. 1023]   = compact match src list (MAXG)
//  [1024 .. 19455] = per-scan-block match regions (NB_SCAN x PBM_STRIDE)
//  [65536 ..]      = per-count-block degree partials (NB_CNT x (MAXG+1))
#define OFF_M    16
#define OFF_CM   512
#define OFF_PBM  1024
#define OFF_PBC  65536

__device__ __forceinline__ float ldf(const void* p, long long i, bool b16) {
    if (b16) {
        unsigned short u = ((const unsigned short*)p)[i];
        return __uint_as_float(((unsigned int)u) << 16);
    }
    return ((const float*)p)[i];
}

__device__ __forceinline__ void ld2(const void* p, long long i, bool b16, float& a, float& b) {
    if (b16) {
        unsigned int u = ((const unsigned int*)p)[i >> 1];
        a = __uint_as_float(u << 16);
        b = __uint_as_float(u & 0xffff0000u);
    } else {
        float2 v = ((const float2*)p)[i >> 1];
        a = v.x; b = v.y;
    }
}

// detect int64 edges: odd 32-bit words of first 64 values all zero. Wave 0 only.
__device__ __forceinline__ int detect_i64(const void* edges, int tid, int* s_flag) {
    if (tid < 64) {
        const unsigned int* w = (const unsigned int*)edges;
        unsigned long long b = __ballot(w[2 * tid + 1] == 0u);
        if (tid == 0) *s_flag = (b == 0xFFFFFFFFFFFFFFFFULL) ? 1 : 0;
    }
    __syncthreads();
    return *s_flag;
}

__global__ void __launch_bounds__(256) k_scan(const void* edges, const int* agent_p, int* wsi) {
    __shared__ int s_pref[256];
    __shared__ int s_list[64];
    __shared__ int s_flag;
    int tid = threadIdx.x;
    int i64 = detect_i64(edges, tid, &s_flag);
    int agent = agent_p[0];
    long long base = (long long)blockIdx.x * 256 + tid;
    const long long stride = (long long)NB_SCAN * 256;

    int c = 0;
    if (i64) {
        const long long* dst = (const long long*)edges + N_EDGES;
        for (long long e = base; e < N_EDGES; e += stride) c += ((int)dst[e] == agent);
    } else {
        const int* dst = (const int*)edges + N_EDGES;
        for (long long e = base; e < N_EDGES; e += stride) c += (dst[e] == agent);
    }
    s_pref[tid] = c;
    __syncthreads();
    #pragma unroll
    for (int off = 1; off < 256; off <<= 1) {
        int v = (tid >= off) ? s_pref[tid - off] : 0;
        __syncthreads();
        s_pref[tid] += v;
        __syncthreads();
    }
    int excl = s_pref[tid] - c;
    int total = s_pref[255];
    if (c > 0 && excl < 64) {
        int k = excl;
        if (i64) {
            const long long* src = (const long long*)edges;
            const long long* dst = src + N_EDGES;
            for (long long e = base; e < N_EDGES; e += stride)
                if ((int)dst[e] == agent) { if (k < 64) s_list[k] = (int)src[e]; k++; }
        } else {
            const int* src = (const int*)edges;
            const int* dst = src + N_EDGES;
            for (long long e = base; e < N_EDGES; e += stride)
                if (dst[e] == agent) { if (k < 64) s_list[k] = src[e]; k++; }
        }
    }
    __syncthreads();
    int* reg = wsi + OFF_PBM + blockIdx.x * PBM_STRIDE;
    int tw = total < 64 ? total : 64;
    if (tid == 0) reg[0] = tw;
    if (tid < tw) reg[1 + tid] = s_list[tid];
}

__global__ void __launch_bounds__(256) k_count(const void* edges, const int* agent_p, int* wsi) {
    __shared__ int s_pref[256];
    __shared__ int s_nodes[MAXG + 1];
    __shared__ int s_cnt[MAXG + 1];
    __shared__ int s_flag;
    int tid = threadIdx.x;
    int i64 = detect_i64(edges, tid, &s_flag);

    // rebuild compact match list (deterministic: scan-block order)
    int bc = wsi[OFF_PBM + tid * PBM_STRIDE];
    bc = bc < 64 ? bc : 64;
    int myc = bc;
    s_pref[tid] = bc;
    __syncthreads();
    #pragma unroll
    for (int off = 1; off < 256; off <<= 1) {
        int v = (tid >= off) ? s_pref[tid - off] : 0;
        __syncthreads();
        s_pref[tid] += v;
        __syncthreads();
    }
    int excl = s_pref[tid] - myc;
    int mc = s_pref[255];
    int m = mc < MAXG ? mc : MAXG;
    for (int i = 0; i < myc; i++) {
        int g = excl + i;
        if (g < MAXG) s_nodes[1 + g] = wsi[OFF_PBM + tid * PBM_STRIDE + 1 + i];
    }
    if (tid == 0) s_nodes[0] = agent_p[0];
    for (int i = tid; i <= m; i += 256) s_cnt[i] = 0;
    __syncthreads();

    long long base = (long long)blockIdx.x * 256 + tid;
    const long long stride = (long long)NB_CNT * 256;
    if (i64) {
        const long long* dst = (const long long*)edges + N_EDGES;
        for (long long e = base; e < N_EDGES; e += stride) {
            int d = (int)dst[e];
            for (int j = 0; j <= m; j++)
                if (d == s_nodes[j]) atomicAdd(&s_cnt[j], 1);
        }
    } else {
        const int* dst = (const int*)edges + N_EDGES;
        for (long long e = base; e < N_EDGES; e += stride) {
            int d = dst[e];
            for (int j = 0; j <= m; j++)
                if (d == s_nodes[j]) atomicAdd(&s_cnt[j], 1);
        }
    }
    __syncthreads();
    int* pbc = wsi + OFF_PBC + blockIdx.x * (MAXG + 1);
    for (int i = tid; i <= m; i += 256) pbc[i] = s_cnt[i];
    if (blockIdx.x == 0) {
        if (tid == 0) wsi[OFF_M] = m;
        for (int i = tid; i < m; i += 256) wsi[OFF_CM + i] = s_nodes[1 + i];
    }
}

__device__ __forceinline__ float sum256b(const float* buf, int tid, float* s_scal) {
    __syncthreads();
    if (tid < 64) {
        float x = buf[tid] + buf[tid + 64] + buf[tid + 128] + buf[tid + 192];
        #pragma unroll
        for (int o = 32; o > 0; o >>= 1) x += __shfl_down(x, o);
        if (tid == 0) *s_scal = x;
    }
    __syncthreads();
    return *s_scal;
}

__global__ void __launch_bounds__(1024) k_mlp(
    const void* state, const int* agent_p,
    const void* conv_w, const void* conv_b,
    const void* fc1_w, const void* fc1_b, const void* ln1_w, const void* ln1_b,
    const void* fc2_w, const void* fc2_b, const void* ln2_w, const void* ln2_b,
    const void* mu_w, const void* mu_b,
    const int* wsi, void* out)
{
    __shared__ float s_wgt[MAXG];
    __shared__ int   s_src[MAXG];
    __shared__ int   s_deg[MAXG + 1];
    __shared__ float scratch[2048];
    __shared__ float xs[D_IN];
    __shared__ float v1[D_HID];
    __shared__ float v2[D_HID];
    __shared__ float s_scal;
    __shared__ int   s_b16;

    int tid = threadIdx.x;
    if (tid < 64) {
        const unsigned short* s = (const unsigned short*)state;
        unsigned short v = s[tid];
        int e = (v >> 7) & 0xff;
        unsigned long long b = __ballot(v == 0 || (e >= 90 && e <= 140));
        if (tid == 0) s_b16 = (b == 0xFFFFFFFFFFFFFFFFULL) ? 1 : 0;
    }
    int m = wsi[OFF_M];
    for (int i = tid; i <= m; i += 1024) s_deg[i] = 0;
    for (int i = tid; i < m; i += 1024) s_src[i] = wsi[OFF_CM + i];
    __syncthreads();

    // reduce per-block degree partials: (m+1) nodes x 8 chunks of 64 blocks
    for (int idx = tid; idx < (m + 1) * 8; idx += 1024) {
        int j = idx >> 3, b0 = (idx & 7) * 64;
        int p = 0;
        #pragma unroll 8
        for (int b = b0; b < b0 + 64; b++) p += wsi[OFF_PBC + b * (MAXG + 1) + j];
        atomicAdd(&s_deg[j], p);
    }
    __syncthreads();
    bool b16 = s_b16 != 0;
    int agent = agent_p[0];
    float dinv_a = rsqrtf((float)(s_deg[0] + 1));
    for (int i = tid; i < m; i += 1024) s_wgt[i] = dinv_a * rsqrtf((float)(s_deg[1 + i] + 1));
    __syncthreads();

    // Phase 1: xsum[128] gather, 16 j-groups x 64 d-pairs
    {
        int jg = tid >> 6;
        int d2 = (tid & 63) * 2;
        float a0 = 0.0f, a1 = 0.0f;
        if (jg == 0) {
            float sa, sb;
            ld2(state, (long long)agent * D_IN + d2, b16, sa, sb);
            a0 = dinv_a * dinv_a * sa;
            a1 = dinv_a * dinv_a * sb;
        }
        for (int j = jg; j < m; j += 16) {
            int s = s_src[j];
            float w = s_wgt[j];
            float sa, sb;
            ld2(state, (long long)s * D_IN + d2, b16, sa, sb);
            a0 += w * sa;
            a1 += w * sb;
        }
        scratch[jg * 128 + d2]     = a0;
        scratch[jg * 128 + d2 + 1] = a1;
    }
    __syncthreads();
    if (tid < D_IN) {
        float acc = 0.0f;
        #pragma unroll
        for (int g = 0; g < 16; g++) acc += scratch[g * 128 + tid];
        xs[tid] = acc;
    }
    __syncthreads();

    // Phase 2: conv matvec 128->256
    {
        int og = tid & 127;
        int ks = tid >> 7;
        int o2 = og * 2;
        float a0 = 0.0f, a1 = 0.0f;
        int kbeg = ks * 16;
        #pragma unroll 8
        for (int k = kbeg; k < kbeg + 16; k++) {
            float xv = xs[k];
            float w0, w1;
            ld2(conv_w, (long long)k * D_HID + o2, b16, w0, w1);
            a0 += xv * w0;
            a1 += xv * w1;
        }
        scratch[ks * 256 + o2]     = a0;
        scratch[ks * 256 + o2 + 1] = a1;
    }
    __syncthreads();
    if (tid < D_HID) {
        float h = ldf(conv_b, tid, b16);
        #pragma unroll
        for (int s = 0; s < 8; s++) h += scratch[s * 256 + tid];
        v1[tid] = fmaxf(h, 0.0f);
    }
    __syncthreads();

    // Phase 3 & 4: fc layers 256->256 with LN+relu
    const void* fw[2]  = { fc1_w, fc2_w };
    const void* fb[2]  = { fc1_b, fc2_b };
    const void* lw[2]  = { ln1_w, ln2_w };
    const void* lb[2]  = { ln1_b, ln2_b };
    float* vin  = v1;
    float* vout = v2;
    for (int L = 0; L < 2; L++) {
        {
            int og = tid & 127;
            int ks = tid >> 7;
            int o2 = og * 2;
            float a0 = 0.0f, a1 = 0.0f;
            int kbeg = ks * 32;
            #pragma unroll 8
            for (int k = kbeg; k < kbeg + 32; k++) {
                float xv = vin[k];
                float w0, w1;
                ld2(fw[L], (long long)k * D_HID + o2, b16, w0, w1);
                a0 += xv * w0;
                a1 += xv * w1;
            }
            scratch[ks * 256 + o2]     = a0;
            scratch[ks * 256 + o2 + 1] = a1;
        }
        __syncthreads();
        float h = 0.0f;
        if (tid < D_HID) {
            h = ldf(fb[L], tid, b16);
            #pragma unroll
            for (int s = 0; s < 8; s++) h += scratch[s * 256 + tid];
            scratch[tid] = h;
        }
        float mu = sum256b(scratch, tid, &s_scal) * (1.0f / D_HID);
        float d = h - mu;
        if (tid < D_HID) scratch[tid] = d * d;
        float var = sum256b(scratch, tid, &s_scal) * (1.0f / D_HID);
        if (tid < D_HID) {
            float y = d * rsqrtf(var + 1e-5f) * ldf(lw[L], tid, b16) + ldf(lb[L], tid, b16);
            vout[tid] = fmaxf(y, 0.0f);
        }
        __syncthreads();
        float* t = vin; vin = vout; vout = t;
    }

    // Phase 5: mu head 256->8, sigmoid
    if (tid < 64) {
        int o = tid & 7;
        int ks = tid >> 3;
        float acc = 0.0f;
        int kbeg = ks * 32;
        #pragma unroll 8
        for (int k = kbeg; k < kbeg + 32; k++)
            acc += vin[k] * ldf(mu_w, (long long)k * 8 + o, b16);
        scratch[ks * 8 + o] = acc;
    }
    __syncthreads();
    if (tid < 8) {
        float acc = ldf(mu_b, tid, b16);
        #pragma unroll
        for (int s = 0; s < 8; s++) acc += scratch[s * 8 + tid];
        float r = 1.0f / (1.0f + expf(-acc));
        if (b16) ((__hip_bfloat16*)out)[tid] = __float2bfloat16(r);
        else     ((float*)out)[tid] = r;
    }
}

extern "C" void kernel_launch(void* const* d_in, const int* in_sizes, int n_in,
                              void* d_out, int out_size, void* d_ws, size_t ws_size,
                              hipStream_t stream) {
    const void* state = d_in[0];
    const void* edges = d_in[1];
    const int* agent = (const int*)d_in[2];
    int* wsi = (int*)d_ws;

    k_scan<<<NB_SCAN, 256, 0, stream>>>(edges, agent, wsi);
    k_count<<<NB_CNT, 256, 0, stream>>>(edges, agent, wsi);
    k_mlp<<<1, 1024, 0, stream>>>(state, agent,
                                  d_in[3], d_in[4],
                                  d_in[5], d_in[6], d_in[7], d_in[8],
                                  d_in[9], d_in[10], d_in[11], d_in[12],
                                  d_in[13], d_in[14],
                                  wsi, d_out);
}